// Round 5
// baseline (135.084 us; speedup 1.0000x reference)
//
#include <hip/hip_runtime.h>

// image (1,1024,1024) f32, x (16,1,1024,1024) f32, W_KL (9,1,3,3) f32, b_KL (9,) f32.
// y[b,h,w] = sum_{a,d} (conv(image,W_KL)[a*3+d][h,w] + b[a*3+d]) * x[b,h+a-1,w+d-1]
#define IH 1024
#define IW 1024
#define NB 16

typedef float v4f __attribute__((ext_vector_type(4)));

// exact-count vmcnt wait (immediate must be a literal token)
#define VMWAIT(n) asm volatile("s_waitcnt vmcnt(" #n ")" ::: "memory")

__device__ __forceinline__ void glds16(const float* g, float* l) {
    __builtin_amdgcn_global_load_lds(
        (const __attribute__((address_space(1))) void*)g,
        (__attribute__((address_space(3))) void*)l, 16, 0, 0);
}

// Image window in registers: aligned v4f core + scalar halo dwords, rows
// clamped in-bounds; zero-padding applied in fin_win_img.
struct RawWin { v4f mv[3]; float fl[3]; float fr[3]; };

__device__ __forceinline__ void issue_win(const float* __restrict__ plane,
                                          int h, int w0, RawWin& rw) {
#pragma unroll
    for (int a = 0; a < 3; ++a) {
        const int hh = h + a - 1;
        const int hc = (hh < 0) ? 0 : (hh >= IH ? IH - 1 : hh);
        const float* rowp = plane + (size_t)hc * IW;
        rw.fl[a] = rowp[w0 > 0 ? w0 - 1 : 0];
        rw.mv[a] = *(const v4f*)(rowp + w0);
        rw.fr[a] = rowp[w0 + 4 < IW ? w0 + 4 : IW - 1];
    }
}

__device__ __forceinline__ void fin_win_img(const RawWin& rw, int h, int w0,
                                            float win[3][6]) {
#pragma unroll
    for (int a = 0; a < 3; ++a) {
        const int hh = h + a - 1;
        const bool rowok = (hh >= 0) & (hh < IH);
        win[a][0] = (rowok && w0 > 0)      ? rw.fl[a]   : 0.f;
        win[a][1] = rowok ? rw.mv[a].x : 0.f;
        win[a][2] = rowok ? rw.mv[a].y : 0.f;
        win[a][3] = rowok ? rw.mv[a].z : 0.f;
        win[a][4] = rowok ? rw.mv[a].w : 0.f;
        win[a][5] = (rowok && w0 + 4 < IW) ? rw.fr[a]   : 0.f;
    }
}

// Block = 4 rows x 256 cols. Each wave owns ONE row and stages its own
// 3-row window (rows h-1..h+1, 256-col slice) into a WAVE-PRIVATE LDS
// region via global_load_lds -> zero cross-wave deps -> NO barriers at all
// (round 4 had 16 lockstep s_barriers). Triple-buffered: stage(b+2) is
// issued in iter b and waited on in iter b+2, so HBM latency hides under
// TWO compute phases instead of one. All waits are counted vmcnt: the
// per-iteration VMEM group is exactly [store(b-1), stage(b+2) x3,
// halo(b+2) x6] = 10 ops, so waiting for batch b's data = skip the two
// younger groups -> vmcnt(20) steady-state (18/19 in prologue, 11/2 at tail).
__global__ __launch_bounds__(256, 4) void fused_nobar(
    const float* __restrict__ image,
    const float* __restrict__ x,
    const float* __restrict__ Wk,
    const float* __restrict__ bk,
    float* __restrict__ out)
{
    __shared__ float lds[4][3][3][256];       // [wave][buf][row][col] 36 KiB -> 4 blk/CU

    const int tx = threadIdx.x;               // lane 0..63
    const int wv = threadIdx.y;               // wave 0..3 = row within group

    // XCD-band swizzle (round-4 verified): xcd = hwid%8 owns a contiguous
    // band of 128 rows, so waves sharing staging rows hit the same L2.
    const int hwid  = blockIdx.x;             // 0..1023
    const int xcd   = hwid & 7;
    const int chunk = hwid >> 3;              // 0..127
    const int bx    = chunk & 3;              // col-tile 0..3
    const int g     = xcd * 32 + (chunk >> 2);// row-group 0..255 (bijective)
    const int c0    = bx * 256;
    const int h     = g * 4 + wv;             // this wave's output row
    const int lc    = tx * 4;                 // local col of first out px
    const int w0    = c0 + lc;                // global col

    const size_t plane = (size_t)IH * IW;

    // Opaque zero in a VGPR: forces halo broadcast loads to stay VMEM
    // (scalarization to SMEM would silently break the vmcnt group counts).
    int zv; asm("v_mov_b32 %0, 0" : "=v"(zv));

    // wave-private stage: rows h-1..h+1 (clamped; pad rows masked via Kv).
    auto stage = [&](int b, int buf) {
        const float* xb = x + (size_t)b * plane;
#pragma unroll
        for (int a = 0; a < 3; ++a) {
            int gr = h + a - 1; gr = gr < 0 ? 0 : (gr > IH - 1 ? IH - 1 : gr);
            glds16(xb + (size_t)gr * IW + c0 + tx * 4, &lds[wv][buf][a][0]);
        }
    };
    // column-halo: cols c0-1 / c0+256 for the 3 rows, 6 broadcast VMEM loads.
    auto halo = [&](int b, float* HL, float* HR) {
        const float* xb = x + (size_t)b * plane;
        const int cl = (c0 > 0) ? c0 - 1 : 0;
        const int cr = (c0 + 256 < IW) ? c0 + 256 : IW - 1;
#pragma unroll
        for (int a = 0; a < 3; ++a) {
            int gr = h + a - 1; gr = gr < 0 ? 0 : (gr > IH - 1 ? IH - 1 : gr);
            const float* rp = xb + (size_t)gr * IW;
            HL[a] = rp[cl + zv];
            HR[a] = rp[cr + zv];
        }
    };

    // ---- issue order (vmcnt groups): [img x9][stage0+halo0 x9][stage1+halo1 x9]
    RawWin rimg;
    issue_win(image, h, w0, rimg);
    __builtin_amdgcn_sched_barrier(0);
    float hl[3][3], hr[3][3];
    stage(0, 0); halo(0, hl[0], hr[0]);
    stage(1, 1); halo(1, hl[1], hr[1]);
    __builtin_amdgcn_sched_barrier(0);

    // conv weights / bias: uniform -> SGPR (lgkmcnt, invisible to vmcnt math)
    float wkk[81];
#pragma unroll
    for (int i = 0; i < 81; ++i) wkk[i] = Wk[i];
    float bb[9];
#pragma unroll
    for (int c = 0; c < 9; ++c) bb[c] = bk[c];

    // ---- K phase (compiler waits vmcnt(18): retires img, keeps stages flying)
    float p[3][6];
    fin_win_img(rimg, h, w0, p);
    float Kv[4][9];
#pragma unroll
    for (int j = 0; j < 4; ++j)
#pragma unroll
        for (int c = 0; c < 9; ++c) {
            float acc = bb[c];
#pragma unroll
            for (int a = 0; a < 3; ++a)
#pragma unroll
                for (int d = 0; d < 3; ++d)
                    acc = fmaf(wkk[c * 9 + a * 3 + d], p[a][j + d], acc);
            Kv[j][c] = acc;
        }
    // Row-pad masking folded into Kv (staged clamp-row garbage then adds 0).
    {
        const bool top = (h == 0);
        const bool bot = (h == IH - 1);
#pragma unroll
        for (int j = 0; j < 4; ++j)
#pragma unroll
            for (int d = 0; d < 3; ++d) {
                Kv[j][d]     = top ? 0.f : Kv[j][d];
                Kv[j][6 + d] = bot ? 0.f : Kv[j][6 + d];
            }
    }

    v4f yprev;
    float* obp = out + (size_t)h * IW + w0;
    const int ll = (tx > 0)  ? lc - 4 : 0;    // aligned left-halo b128
    const int lr = (tx < 63) ? lc + 4 : 252;  // aligned right-halo b128

#pragma unroll
    for (int b = 0; b < NB; ++b) {
        // per-iter VMEM group: [store(b-1), stage(b+2) x3, halo(b+2) x6]
        if (b > 0)
            __builtin_nontemporal_store(yprev,
                                        (v4f*)(obp + (size_t)(b - 1) * plane));
        if (b + 2 < NB) {
            stage(b + 2, (b + 2) % 3);
            halo(b + 2, hl[(b + 2) % 3], hr[(b + 2) % 3]);
        }
        // counted wait for batch b's stage+halo; groups b+1,b+2 stay in flight
        if      (b == 0)  VMWAIT(18);
        else if (b == 1)  VMWAIT(19);
        else if (b == 14) VMWAIT(11);
        else if (b == 15) VMWAIT(2);
        else              VMWAIT(20);
        __builtin_amdgcn_sched_barrier(0);

        // ---- consume batch b from wave-private lds[wv][b%3] ----
        const float* lb = &lds[wv][b % 3][0][0];
        float win[3][6];
#pragma unroll
        for (int a = 0; a < 3; ++a) {
            const float* rowp = lb + a * 256;
            const v4f lv = *(const v4f*)(rowp + ll);
            const v4f mv = *(const v4f*)(rowp + lc);
            const v4f rv = *(const v4f*)(rowp + lr);
            const float le = (tx == 0)  ? hl[b % 3][a] : lv.w;
            const float re = (tx == 63) ? hr[b % 3][a] : rv.x;
            win[a][0] = (w0 > 0)      ? le : 0.f;
            win[a][1] = mv.x; win[a][2] = mv.y;
            win[a][3] = mv.z; win[a][4] = mv.w;
            win[a][5] = (w0 + 4 < IW) ? re : 0.f;
        }
        v4f yy;
#pragma unroll
        for (int j = 0; j < 4; ++j) {
            float acc = 0.f;
#pragma unroll
            for (int a = 0; a < 3; ++a)
#pragma unroll
                for (int d = 0; d < 3; ++d)
                    acc = fmaf(Kv[j][a * 3 + d], win[a][j + d], acc);
            yy[j] = acc;
        }
        yprev = yy;
    }
    __builtin_nontemporal_store(yprev,
                                (v4f*)(obp + (size_t)(NB - 1) * plane));
}

extern "C" void kernel_launch(void* const* d_in, const int* in_sizes, int n_in,
                              void* d_out, int out_size, void* d_ws, size_t ws_size,
                              hipStream_t stream) {
    const float* image = (const float*)d_in[0]; // 1*1024*1024
    const float* x     = (const float*)d_in[1]; // 16*1*1024*1024
    const float* Wk    = (const float*)d_in[2]; // 9*1*3*3
    const float* bk    = (const float*)d_in[3]; // 9
    float* out = (float*)d_out;                 // 16*1024*1024 f32

    dim3 block(64, 4);
    dim3 grid(1024);                            // 4 blocks/CU, uniform work
    fused_nobar<<<grid, block, 0, stream>>>(image, x, Wk, bk, out);
}